// Round 3
// baseline (940.020 us; speedup 1.0000x reference)
//
#include <hip/hip_runtime.h>
#include <hip/hip_bf16.h>

#define B_ 32
#define S_ 256
#define E_ 768
#define H_ 32
#define D_ 24

typedef __hip_bfloat16 bf16;

// ---------------------------------------------------------------------------
// prep: Wvx[e][x*32+h] = sum_c Wv[e][h*24+c] * Wf_x[h*24+c]   (768 x 96, f32)
//       bvx[x*32+h]    = sum_c bv[h*24+c]    * Wf_x[h*24+c]   (96, f32)
// ---------------------------------------------------------------------------
__global__ __launch_bounds__(256) void prep_kernel(
    const float* __restrict__ Wv, const float* __restrict__ bv,
    const float* __restrict__ Wfx, const float* __restrict__ Wfy,
    const float* __restrict__ Wfz,
    float* __restrict__ Wvx, float* __restrict__ bvx)
{
  int gid = blockIdx.x * 256 + threadIdx.x;
  if (gid < E_ * 96) {
    int e = gid / 96, n = gid % 96;
    int x = n >> 5, h = n & 31;
    const float* Wf = (x == 0) ? Wfx : (x == 1 ? Wfy : Wfz);
    float s = 0.f;
    #pragma unroll
    for (int c = 0; c < D_; c++)
      s += Wv[e * E_ + h * D_ + c] * Wf[h * D_ + c];
    Wvx[e * 96 + n] = s;
  } else {
    int g2 = gid - E_ * 96;
    if (g2 < 96) {
      int x = g2 >> 5, h = g2 & 31;
      const float* Wf = (x == 0) ? Wfx : (x == 1 ? Wfy : Wfz);
      float s = 0.f;
      #pragma unroll
      for (int c = 0; c < D_; c++)
        s += bv[h * D_ + c] * Wf[h * D_ + c];
      bvx[g2] = s;
    }
  }
}

// ---------------------------------------------------------------------------
// Tiled GEMM: C[M,N] = (A[M,K] @ Bw[K,N] + bias) * scale, fp32 accumulate.
// mode 0: bf16 out in (b,h,s,d) layout for q/k.  mode 2: f32 out, vw layout
// [x][b][h][s].  BM=BN=64, BK=16, 256 threads, 4x4 per thread.
// ---------------------------------------------------------------------------
__global__ __launch_bounds__(256) void gemm_proj(
    const float* __restrict__ A, const float* __restrict__ Bw,
    const float* __restrict__ bias, void* __restrict__ outp,
    int M, int N, int K, float scale, int mode)
{
  __shared__ __align__(16) float As[16][68];
  __shared__ __align__(16) float Bs[16][68];
  int tid = threadIdx.x;
  int m0 = blockIdx.y * 64;
  int n0 = blockIdx.x * 64;
  int tm = tid >> 4, tn = tid & 15;
  int a_mm = tid >> 2, a_k0 = (tid & 3) * 4;
  int b_r = tid >> 6, b_c = tid & 63;
  float acc[4][4] = {};

  for (int k0 = 0; k0 < K; k0 += 16) {
    float4 av4 = *reinterpret_cast<const float4*>(
        A + (size_t)(m0 + a_mm) * K + k0 + a_k0);
    As[a_k0 + 0][a_mm] = av4.x;
    As[a_k0 + 1][a_mm] = av4.y;
    As[a_k0 + 2][a_mm] = av4.z;
    As[a_k0 + 3][a_mm] = av4.w;
    #pragma unroll
    for (int r = 0; r < 4; r++) {
      int kk = b_r * 4 + r;
      int n = n0 + b_c;
      float v = 0.f;
      if (n < N) v = Bw[(size_t)(k0 + kk) * N + n];
      Bs[kk][b_c] = v;
    }
    __syncthreads();
    #pragma unroll
    for (int kk = 0; kk < 16; kk++) {
      float4 av = *reinterpret_cast<const float4*>(&As[kk][tm * 4]);
      float4 bv4 = *reinterpret_cast<const float4*>(&Bs[kk][tn * 4]);
      float a_[4] = {av.x, av.y, av.z, av.w};
      float b_[4] = {bv4.x, bv4.y, bv4.z, bv4.w};
      #pragma unroll
      for (int i = 0; i < 4; i++)
        #pragma unroll
        for (int j = 0; j < 4; j++)
          acc[i][j] += a_[i] * b_[j];
    }
    __syncthreads();
  }

  #pragma unroll
  for (int i = 0; i < 4; i++) {
    int m = m0 + tm * 4 + i;
    int b = m >> 8, s = m & 255;
    #pragma unroll
    for (int j = 0; j < 4; j++) {
      int n = n0 + tn * 4 + j;
      if (n < N) {
        float val = (acc[i][j] + bias[n]) * scale;
        if (mode == 2) {
          int x = n >> 5, h = n & 31;
          ((float*)outp)[(((size_t)x * B_ + b) * H_ + h) * S_ + s] = val;
        } else {
          int h = n / 24, d = n - h * 24;
          ((bf16*)outp)[(((size_t)b * H_ + h) * S_ + s) * D_ + d] = (bf16)val;
        }
      }
    }
  }
}

// ---------------------------------------------------------------------------
// Attention: one block per (b,h). k/q/vw staged in LDS (pad 25 -> conflict
// free). Each wave owns s = wave, wave+4, ... : wave-shuffle softmax, then
// out[b,s,x] += sum_t probs[t] * dp[b,s,t,x] * vw_x[b,h,t]  via atomicAdd
// directly into the fp32 output.
// ---------------------------------------------------------------------------
__global__ __launch_bounds__(256) void attn_kernel(
    const bf16* __restrict__ qg, const bf16* __restrict__ kg,
    const float* __restrict__ vwg, const float* __restrict__ biasg,
    const float* __restrict__ dpg, float* __restrict__ out)
{
  __shared__ float ql[S_ * 25];
  __shared__ float kl[S_ * 25];
  __shared__ float vwl[3][S_];
  int bh = blockIdx.x;
  int b = bh >> 5, h = bh & 31;
  int tid = threadIdx.x;
  {
    const bf16* qrow = qg + ((size_t)bh * S_ + tid) * D_;
    const bf16* krow = kg + ((size_t)bh * S_ + tid) * D_;
    #pragma unroll
    for (int d = 0; d < D_; d++) {
      ql[tid * 25 + d] = (float)qrow[d];
      kl[tid * 25 + d] = (float)krow[d];
    }
    #pragma unroll
    for (int x = 0; x < 3; x++)
      vwl[x][tid] = vwg[(((size_t)x * B_ + b) * H_ + h) * S_ + tid];
  }
  __syncthreads();

  int wave = tid >> 6, lane = tid & 63;
  const float* biasbh = biasg + (size_t)bh * S_ * S_;

  for (int s = wave; s < S_; s += 4) {
    float qreg[D_];
    #pragma unroll
    for (int d = 0; d < D_; d++) qreg[d] = ql[s * 25 + d];

    float sc[4];
    #pragma unroll
    for (int j = 0; j < 4; j++) {
      int t = lane + 64 * j;
      float a = biasbh[s * S_ + t];
      #pragma unroll
      for (int d = 0; d < D_; d++) a += qreg[d] * kl[t * 25 + d];
      sc[j] = a;
    }
    float mx = fmaxf(fmaxf(sc[0], sc[1]), fmaxf(sc[2], sc[3]));
    #pragma unroll
    for (int o = 32; o; o >>= 1) mx = fmaxf(mx, __shfl_xor(mx, o));
    float p[4], l = 0.f;
    #pragma unroll
    for (int j = 0; j < 4; j++) { p[j] = __expf(sc[j] - mx); l += p[j]; }
    #pragma unroll
    for (int o = 32; o; o >>= 1) l += __shfl_xor(l, o);
    float inv = 1.0f / l;

    float ax = 0.f, ay = 0.f, az = 0.f;
    const float* dprow = dpg + ((size_t)(b * S_ + s) * S_) * 3;
    #pragma unroll
    for (int j = 0; j < 4; j++) {
      int t = lane + 64 * j;
      float w = p[j] * inv;
      float dx = dprow[t * 3 + 0];
      float dy = dprow[t * 3 + 1];
      float dz = dprow[t * 3 + 2];
      ax += w * dx * vwl[0][t];
      ay += w * dy * vwl[1][t];
      az += w * dz * vwl[2][t];
    }
    #pragma unroll
    for (int o = 32; o; o >>= 1) {
      ax += __shfl_xor(ax, o);
      ay += __shfl_xor(ay, o);
      az += __shfl_xor(az, o);
    }
    if (lane == 0) {
      float* op = out + (size_t)(b * S_ + s) * 3;
      atomicAdd(op + 0, ax);
      atomicAdd(op + 1, ay);
      atomicAdd(op + 2, az);
    }
  }
}

// ---------------------------------------------------------------------------
extern "C" void kernel_launch(void* const* d_in, const int* in_sizes, int n_in,
                              void* d_out, int out_size, void* d_ws, size_t ws_size,
                              hipStream_t stream)
{
  const float* feats     = (const float*)d_in[0];
  const float* attn_bias = (const float*)d_in[1];
  const float* delta_pos = (const float*)d_in[2];
  const float* Wq        = (const float*)d_in[3];
  const float* bq        = (const float*)d_in[4];
  const float* Wk        = (const float*)d_in[5];
  const float* bk        = (const float*)d_in[6];
  const float* Wv        = (const float*)d_in[7];
  const float* bv        = (const float*)d_in[8];
  const float* Wfx       = (const float*)d_in[9];
  const float* Wfy       = (const float*)d_in[10];
  const float* Wfz       = (const float*)d_in[11];

  char* ws = (char*)d_ws;
  size_t off = 0;
  auto alloc = [&](size_t bytes) -> void* {
    void* p = ws + off;
    off = (off + bytes + 255) & ~(size_t)255;
    return p;
  };
  bf16*  ws_q   = (bf16*) alloc((size_t)B_ * H_ * S_ * D_ * 2);
  bf16*  ws_k   = (bf16*) alloc((size_t)B_ * H_ * S_ * D_ * 2);
  float* ws_vw  = (float*)alloc((size_t)3 * B_ * H_ * S_ * 4);
  float* ws_Wvx = (float*)alloc((size_t)E_ * 96 * 4);
  float* ws_bvx = (float*)alloc(96 * 4);

  // d_out is fp32 (reference output dtype). It is poisoned before timed
  // launches, so zero it ourselves; attn_kernel accumulates into it.
  hipMemsetAsync(d_out, 0, (size_t)B_ * S_ * 3 * 4, stream);

  prep_kernel<<<289, 256, 0, stream>>>(Wv, bv, Wfx, Wfy, Wfz, ws_Wvx, ws_bvx);

  const float qscale = 0.20412414523193154f;  // 24^-0.5
  gemm_proj<<<dim3(12, 128), 256, 0, stream>>>(feats, Wq, bq, ws_q,
                                               B_ * S_, E_, E_, qscale, 0);
  gemm_proj<<<dim3(12, 128), 256, 0, stream>>>(feats, Wk, bk, ws_k,
                                               B_ * S_, E_, E_, 1.0f, 0);
  gemm_proj<<<dim3(2, 128), 256, 0, stream>>>(feats, ws_Wvx, ws_bvx, ws_vw,
                                              B_ * S_, 96, E_, 1.0f, 2);

  attn_kernel<<<B_ * H_, 256, 0, stream>>>(ws_q, ws_k, ws_vw, attn_bias,
                                           delta_pos, (float*)d_out);
}

// Round 4
// 655.999 us; speedup vs baseline: 1.4330x; 1.4330x over previous
//
#include <hip/hip_runtime.h>
#include <hip/hip_bf16.h>

#define B_ 32
#define S_ 256
#define E_ 768
#define H_ 32
#define D_ 24
#define NTOT 1664   // 768 (q) + 768 (k) + 96 (vw) + 32 pad
#define LK 40       // LDS row stride (bf16 elems) for 32-wide K tiles

typedef __hip_bfloat16 bf16;
typedef __attribute__((ext_vector_type(8))) short short8;
typedef __attribute__((ext_vector_type(4))) float floatx4;

// ---------------------------------------------------------------------------
// feats fp32 -> bf16, 4 elems/thread
// ---------------------------------------------------------------------------
__global__ __launch_bounds__(256) void cast_feats(
    const float* __restrict__ in, bf16* __restrict__ outp, int n4)
{
  int i = blockIdx.x * 256 + threadIdx.x;
  if (i < n4) {
    float4 v = reinterpret_cast<const float4*>(in)[i];
    union { ushort4 u; bf16 b[4]; } pk;
    pk.b[0] = (bf16)v.x; pk.b[1] = (bf16)v.y;
    pk.b[2] = (bf16)v.z; pk.b[3] = (bf16)v.w;
    reinterpret_cast<ushort4*>(outp)[i] = pk.u;
  }
}

// ---------------------------------------------------------------------------
// Pack transposed bf16 weights Wt[n][k], n in [0,1664):
//   n <  768 : Wq[k][n] * qscale
//   n < 1536 : Wk[k][n-768]
//   n < 1632 : Wvx[k][n-1536] = sum_c Wv[k][h*24+c] * Wf_x[h*24+c]
//   else     : 0
// plus fused bias biasf[1664] (f32).
// ---------------------------------------------------------------------------
__global__ __launch_bounds__(256) void prep_pack(
    const float* __restrict__ Wq, const float* __restrict__ Wk,
    const float* __restrict__ Wv,
    const float* __restrict__ bq, const float* __restrict__ bk,
    const float* __restrict__ bv,
    const float* __restrict__ Wfx, const float* __restrict__ Wfy,
    const float* __restrict__ Wfz,
    bf16* __restrict__ Wt, float* __restrict__ biasf)
{
  const float qscale = 0.20412414523193154f;  // 24^-0.5
  int gid = blockIdx.x * 256 + threadIdx.x;
  if (gid < NTOT * E_) {
    int n = gid / E_, k = gid % E_;
    float val;
    if (n < 768) {
      val = Wq[(size_t)k * E_ + n] * qscale;
    } else if (n < 1536) {
      val = Wk[(size_t)k * E_ + (n - 768)];
    } else if (n < 1632) {
      int nn = n - 1536, x = nn >> 5, h = nn & 31;
      const float* Wf = (x == 0) ? Wfx : (x == 1 ? Wfy : Wfz);
      float s = 0.f;
      #pragma unroll
      for (int c = 0; c < D_; c++)
        s += Wv[(size_t)k * E_ + h * D_ + c] * Wf[h * D_ + c];
      val = s;
    } else {
      val = 0.f;
    }
    Wt[gid] = (bf16)val;
  } else {
    int n = gid - NTOT * E_;
    if (n < NTOT) {
      float val;
      if (n < 768) {
        val = bq[n] * qscale;
      } else if (n < 1536) {
        val = bk[n - 768];
      } else if (n < 1632) {
        int nn = n - 1536, x = nn >> 5, h = nn & 31;
        const float* Wf = (x == 0) ? Wfx : (x == 1 ? Wfy : Wfz);
        float s = 0.f;
        #pragma unroll
        for (int c = 0; c < D_; c++)
          s += bv[h * D_ + c] * Wf[h * D_ + c];
        val = s;
      } else {
        val = 0.f;
      }
      biasf[n] = val;
    }
  }
}

// ---------------------------------------------------------------------------
// MFMA GEMM: C[8192][1664] = A[8192][768](bf16) @ Wt^T + biasf, split epilogue:
//   n<768 -> q (bf16, (b,h,s,d)); n<1536 -> k (same); n<1632 -> vw (f32,
//   [x][b][h][s]); else discard.
// 128x128 tile, BK=32, 256 thr (4 waves, 2x2), 4x4 16x16x32 frags per wave.
// ---------------------------------------------------------------------------
__global__ __launch_bounds__(256) void gemm_qkv(
    const bf16* __restrict__ A, const bf16* __restrict__ Wt,
    const float* __restrict__ biasf,
    bf16* __restrict__ qout, bf16* __restrict__ kout,
    float* __restrict__ vwout)
{
  __shared__ __align__(16) short As[128 * LK];
  __shared__ __align__(16) short Bs[128 * LK];
  int tid = threadIdx.x;
  int m0 = blockIdx.y * 128, n0 = blockIdx.x * 128;
  int lrow = tid >> 2, lcol = (tid & 3) * 8;
  int wave = tid >> 6, lane = tid & 63;
  int wm = (wave >> 1) * 64, wn = (wave & 1) * 64;
  int fr = lane & 15, quad = lane >> 4;

  floatx4 acc[4][4];
  const floatx4 zero = {0.f, 0.f, 0.f, 0.f};
  #pragma unroll
  for (int i = 0; i < 4; i++)
    #pragma unroll
    for (int j = 0; j < 4; j++) acc[i][j] = zero;

  for (int k0 = 0; k0 < E_; k0 += 32) {
    float4 av0 = *reinterpret_cast<const float4*>(
        A + (size_t)(m0 + lrow) * E_ + k0 + lcol);
    float4 av1 = *reinterpret_cast<const float4*>(
        A + (size_t)(m0 + 64 + lrow) * E_ + k0 + lcol);
    float4 bv0 = *reinterpret_cast<const float4*>(
        Wt + (size_t)(n0 + lrow) * E_ + k0 + lcol);
    float4 bv1 = *reinterpret_cast<const float4*>(
        Wt + (size_t)(n0 + 64 + lrow) * E_ + k0 + lcol);
    __syncthreads();  // previous iter's frag reads complete before overwrite
    *reinterpret_cast<float4*>(&As[lrow * LK + lcol]) = av0;
    *reinterpret_cast<float4*>(&As[(lrow + 64) * LK + lcol]) = av1;
    *reinterpret_cast<float4*>(&Bs[lrow * LK + lcol]) = bv0;
    *reinterpret_cast<float4*>(&Bs[(lrow + 64) * LK + lcol]) = bv1;
    __syncthreads();
    short8 af[4], bfr[4];
    #pragma unroll
    for (int t = 0; t < 4; t++)
      af[t] = *reinterpret_cast<const short8*>(
          &As[(wm + t * 16 + fr) * LK + quad * 8]);
    #pragma unroll
    for (int t = 0; t < 4; t++)
      bfr[t] = *reinterpret_cast<const short8*>(
          &Bs[(wn + t * 16 + fr) * LK + quad * 8]);
    #pragma unroll
    for (int ti = 0; ti < 4; ti++)
      #pragma unroll
      for (int tj = 0; tj < 4; tj++)
        acc[ti][tj] = __builtin_amdgcn_mfma_f32_16x16x32_bf16(
            af[ti], bfr[tj], acc[ti][tj], 0, 0, 0);
  }

  // epilogue: C/D layout col = lane&15, row = quad*4 + r
  #pragma unroll
  for (int ti = 0; ti < 4; ti++) {
    #pragma unroll
    for (int tj = 0; tj < 4; tj++) {
      int n = n0 + wn + tj * 16 + fr;
      float bias = biasf[n];
      #pragma unroll
      for (int r = 0; r < 4; r++) {
        int m = m0 + wm + ti * 16 + quad * 4 + r;
        int b = m >> 8, s = m & 255;
        float val = acc[ti][tj][r] + bias;
        if (n < 768) {
          int h = n / 24, d = n - h * 24;
          qout[(((size_t)b * H_ + h) * S_ + s) * D_ + d] = (bf16)val;
        } else if (n < 1536) {
          int n2 = n - 768;
          int h = n2 / 24, d = n2 - h * 24;
          kout[(((size_t)b * H_ + h) * S_ + s) * D_ + d] = (bf16)val;
        } else if (n < 1632) {
          int nn = n - 1536, x = nn >> 5, h = nn & 31;
          vwout[(((size_t)x * B_ + b) * H_ + h) * S_ + s] = val;
        }
      }
    }
  }
}

// ---------------------------------------------------------------------------
// Attention: one block per (b,h). Only k (fp32, pad 25) + vw in LDS ->
// 28.7 KB -> all 4 blocks/CU resident. q rows read from global (broadcast).
// Wave owns s = wave, wave+4, ...: shuffle softmax, then contraction with
// delta_pos and vw, atomicAdd into fp32 d_out.
// ---------------------------------------------------------------------------
__global__ __launch_bounds__(256) void attn_kernel(
    const bf16* __restrict__ qg, const bf16* __restrict__ kg,
    const float* __restrict__ vwg, const float* __restrict__ biasg,
    const float* __restrict__ dpg, float* __restrict__ out)
{
  __shared__ float kl[S_ * 25];
  __shared__ float vwl[3][S_];
  int bh = blockIdx.x;
  int b = bh >> 5, h = bh & 31;
  int tid = threadIdx.x;
  {
    const bf16* krow = kg + ((size_t)bh * S_ + tid) * D_;
    #pragma unroll
    for (int d = 0; d < D_; d++) kl[tid * 25 + d] = (float)krow[d];
    #pragma unroll
    for (int x = 0; x < 3; x++)
      vwl[x][tid] = vwg[(((size_t)x * B_ + b) * H_ + h) * S_ + tid];
  }
  __syncthreads();

  int wave = tid >> 6, lane = tid & 63;
  const float* biasbh = biasg + (size_t)bh * S_ * S_;

  for (int s = wave; s < S_; s += 4) {
    const bf16* qrow = qg + ((size_t)bh * S_ + s) * D_;
    float qreg[D_];
    #pragma unroll
    for (int d = 0; d < D_; d++) qreg[d] = (float)qrow[d];

    float sc[4];
    #pragma unroll
    for (int j = 0; j < 4; j++) {
      int t = lane + 64 * j;
      float a = biasbh[s * S_ + t];
      #pragma unroll
      for (int d = 0; d < D_; d++) a += qreg[d] * kl[t * 25 + d];
      sc[j] = a;
    }
    float mx = fmaxf(fmaxf(sc[0], sc[1]), fmaxf(sc[2], sc[3]));
    #pragma unroll
    for (int o = 32; o; o >>= 1) mx = fmaxf(mx, __shfl_xor(mx, o));
    float p[4], l = 0.f;
    #pragma unroll
    for (int j = 0; j < 4; j++) { p[j] = __expf(sc[j] - mx); l += p[j]; }
    #pragma unroll
    for (int o = 32; o; o >>= 1) l += __shfl_xor(l, o);
    float inv = 1.0f / l;

    float ax = 0.f, ay = 0.f, az = 0.f;
    const float* dprow = dpg + ((size_t)(b * S_ + s) * S_) * 3;
    #pragma unroll
    for (int j = 0; j < 4; j++) {
      int t = lane + 64 * j;
      float w = p[j] * inv;
      float3 dp3 = *reinterpret_cast<const float3*>(&dprow[t * 3]);
      ax += w * dp3.x * vwl[0][t];
      ay += w * dp3.y * vwl[1][t];
      az += w * dp3.z * vwl[2][t];
    }
    #pragma unroll
    for (int o = 32; o; o >>= 1) {
      ax += __shfl_xor(ax, o);
      ay += __shfl_xor(ay, o);
      az += __shfl_xor(az, o);
    }
    if (lane == 0) {
      float* op = out + (size_t)(b * S_ + s) * 3;
      atomicAdd(op + 0, ax);
      atomicAdd(op + 1, ay);
      atomicAdd(op + 2, az);
    }
  }
}

// ---------------------------------------------------------------------------
extern "C" void kernel_launch(void* const* d_in, const int* in_sizes, int n_in,
                              void* d_out, int out_size, void* d_ws, size_t ws_size,
                              hipStream_t stream)
{
  const float* feats     = (const float*)d_in[0];
  const float* attn_bias = (const float*)d_in[1];
  const float* delta_pos = (const float*)d_in[2];
  const float* Wq        = (const float*)d_in[3];
  const float* bq        = (const float*)d_in[4];
  const float* Wk        = (const float*)d_in[5];
  const float* bk        = (const float*)d_in[6];
  const float* Wv        = (const float*)d_in[7];
  const float* bv        = (const float*)d_in[8];
  const float* Wfx       = (const float*)d_in[9];
  const float* Wfy       = (const float*)d_in[10];
  const float* Wfz       = (const float*)d_in[11];

  char* ws = (char*)d_ws;
  size_t off = 0;
  auto alloc = [&](size_t bytes) -> void* {
    void* p = ws + off;
    off = (off + bytes + 255) & ~(size_t)255;
    return p;
  };
  bf16*  ws_fb   = (bf16*) alloc((size_t)B_ * S_ * E_ * 2);        // feats bf16
  bf16*  ws_q    = (bf16*) alloc((size_t)B_ * H_ * S_ * D_ * 2);
  bf16*  ws_k    = (bf16*) alloc((size_t)B_ * H_ * S_ * D_ * 2);
  float* ws_vw   = (float*)alloc((size_t)3 * B_ * H_ * S_ * 4);
  bf16*  ws_Wt   = (bf16*) alloc((size_t)NTOT * E_ * 2);
  float* ws_bias = (float*)alloc((size_t)NTOT * 4);

  // fp32 output accumulated by attn_kernel; poisoned before timed launches
  hipMemsetAsync(d_out, 0, (size_t)B_ * S_ * 3 * 4, stream);

  int n4 = B_ * S_ * E_ / 4;
  cast_feats<<<(n4 + 255) / 256, 256, 0, stream>>>(feats, ws_fb, n4);

  int prep_n = NTOT * E_ + NTOT;
  prep_pack<<<(prep_n + 255) / 256, 256, 0, stream>>>(
      Wq, Wk, Wv, bq, bk, bv, Wfx, Wfy, Wfz, ws_Wt, ws_bias);

  gemm_qkv<<<dim3(NTOT / 128, B_ * S_ / 128), 256, 0, stream>>>(
      ws_fb, ws_Wt, ws_bias, ws_q, ws_k, ws_vw);

  attn_kernel<<<B_ * H_, 256, 0, stream>>>(ws_q, ws_k, ws_vw, attn_bias,
                                           delta_pos, (float*)d_out);
}

// Round 5
// 608.405 us; speedup vs baseline: 1.5451x; 1.0782x over previous
//
#include <hip/hip_runtime.h>
#include <hip/hip_bf16.h>

#define B_ 32
#define S_ 256
#define E_ 768
#define H_ 32
#define D_ 24
#define NTOT 1664   // 768 (q) + 768 (k) + 96 (vw) + 32 pad
#define LK 40       // LDS row stride (bf16 elems) for 32-wide K tiles

typedef __hip_bfloat16 bf16;
typedef __attribute__((ext_vector_type(8))) short short8;
typedef __attribute__((ext_vector_type(4))) float floatx4;
typedef __attribute__((ext_vector_type(2))) float f32x2;

// ---------------------------------------------------------------------------
// feats fp32 -> bf16, 4 elems/thread
// ---------------------------------------------------------------------------
__global__ __launch_bounds__(256) void cast_feats(
    const float* __restrict__ in, bf16* __restrict__ outp, int n4)
{
  int i = blockIdx.x * 256 + threadIdx.x;
  if (i < n4) {
    float4 v = reinterpret_cast<const float4*>(in)[i];
    union { ushort4 u; bf16 b[4]; } pk;
    pk.b[0] = (bf16)v.x; pk.b[1] = (bf16)v.y;
    pk.b[2] = (bf16)v.z; pk.b[3] = (bf16)v.w;
    reinterpret_cast<ushort4*>(outp)[i] = pk.u;
  }
}

// ---------------------------------------------------------------------------
// Pack transposed bf16 weights Wt[n][k] + fused bias biasf[1664].
// ---------------------------------------------------------------------------
__global__ __launch_bounds__(256) void prep_pack(
    const float* __restrict__ Wq, const float* __restrict__ Wk,
    const float* __restrict__ Wv,
    const float* __restrict__ bq, const float* __restrict__ bk,
    const float* __restrict__ bv,
    const float* __restrict__ Wfx, const float* __restrict__ Wfy,
    const float* __restrict__ Wfz,
    bf16* __restrict__ Wt, float* __restrict__ biasf)
{
  const float qscale = 0.20412414523193154f;  // 24^-0.5
  int gid = blockIdx.x * 256 + threadIdx.x;
  if (gid < NTOT * E_) {
    int n = gid / E_, k = gid % E_;
    float val;
    if (n < 768) {
      val = Wq[(size_t)k * E_ + n] * qscale;
    } else if (n < 1536) {
      val = Wk[(size_t)k * E_ + (n - 768)];
    } else if (n < 1632) {
      int nn = n - 1536, x = nn >> 5, h = nn & 31;
      const float* Wf = (x == 0) ? Wfx : (x == 1 ? Wfy : Wfz);
      float s = 0.f;
      #pragma unroll
      for (int c = 0; c < D_; c++)
        s += Wv[(size_t)k * E_ + h * D_ + c] * Wf[h * D_ + c];
      val = s;
    } else {
      val = 0.f;
    }
    Wt[gid] = (bf16)val;
  } else {
    int n = gid - NTOT * E_;
    if (n < NTOT) {
      float val;
      if (n < 768) {
        val = bq[n] * qscale;
      } else if (n < 1536) {
        val = bk[n - 768];
      } else if (n < 1632) {
        int nn = n - 1536, x = nn >> 5, h = nn & 31;
        const float* Wf = (x == 0) ? Wfx : (x == 1 ? Wfy : Wfz);
        float s = 0.f;
        #pragma unroll
        for (int c = 0; c < D_; c++)
          s += bv[h * D_ + c] * Wf[h * D_ + c];
        val = s;
      } else {
        val = 0.f;
      }
      biasf[n] = val;
    }
  }
}

// ---------------------------------------------------------------------------
// MFMA GEMM with 1-stage register prefetch: global loads of tile k+1 issue
// before the MFMA of tile k (vmcnt-wait lands at the next barrier, after
// compute). 128x128 tile, BK=32, 4 waves, 4x4 16x16x32 frags per wave.
// ---------------------------------------------------------------------------
__global__ __launch_bounds__(256) void gemm_qkv(
    const bf16* __restrict__ A, const bf16* __restrict__ Wt,
    const float* __restrict__ biasf,
    bf16* __restrict__ qout, bf16* __restrict__ kout,
    float* __restrict__ vwout)
{
  __shared__ __align__(16) short As[128 * LK];
  __shared__ __align__(16) short Bs[128 * LK];
  int tid = threadIdx.x;
  int m0 = blockIdx.y * 128, n0 = blockIdx.x * 128;
  int lrow = tid >> 2, lcol = (tid & 3) * 8;
  int wave = tid >> 6, lane = tid & 63;
  int wm = (wave >> 1) * 64, wn = (wave & 1) * 64;
  int fr = lane & 15, quad = lane >> 4;

  floatx4 acc[4][4];
  const floatx4 zero = {0.f, 0.f, 0.f, 0.f};
  #pragma unroll
  for (int i = 0; i < 4; i++)
    #pragma unroll
    for (int j = 0; j < 4; j++) acc[i][j] = zero;

  const bf16* Aptr = A + (size_t)(m0 + lrow) * E_ + lcol;
  const bf16* Bptr = Wt + (size_t)(n0 + lrow) * E_ + lcol;
  float4 av0 = *reinterpret_cast<const float4*>(Aptr);
  float4 av1 = *reinterpret_cast<const float4*>(Aptr + (size_t)64 * E_);
  float4 bv0 = *reinterpret_cast<const float4*>(Bptr);
  float4 bv1 = *reinterpret_cast<const float4*>(Bptr + (size_t)64 * E_);

  for (int k0 = 0; k0 < E_; k0 += 32) {
    __syncthreads();  // previous iter's frag reads complete
    *reinterpret_cast<float4*>(&As[lrow * LK + lcol]) = av0;
    *reinterpret_cast<float4*>(&As[(lrow + 64) * LK + lcol]) = av1;
    *reinterpret_cast<float4*>(&Bs[lrow * LK + lcol]) = bv0;
    *reinterpret_cast<float4*>(&Bs[(lrow + 64) * LK + lcol]) = bv1;
    __syncthreads();
    if (k0 + 32 < E_) {  // prefetch next K-tile into registers
      av0 = *reinterpret_cast<const float4*>(Aptr + k0 + 32);
      av1 = *reinterpret_cast<const float4*>(Aptr + (size_t)64 * E_ + k0 + 32);
      bv0 = *reinterpret_cast<const float4*>(Bptr + k0 + 32);
      bv1 = *reinterpret_cast<const float4*>(Bptr + (size_t)64 * E_ + k0 + 32);
    }
    short8 af[4], bfr[4];
    #pragma unroll
    for (int t = 0; t < 4; t++)
      af[t] = *reinterpret_cast<const short8*>(
          &As[(wm + t * 16 + fr) * LK + quad * 8]);
    #pragma unroll
    for (int t = 0; t < 4; t++)
      bfr[t] = *reinterpret_cast<const short8*>(
          &Bs[(wn + t * 16 + fr) * LK + quad * 8]);
    #pragma unroll
    for (int ti = 0; ti < 4; ti++)
      #pragma unroll
      for (int tj = 0; tj < 4; tj++)
        acc[ti][tj] = __builtin_amdgcn_mfma_f32_16x16x32_bf16(
            af[ti], bfr[tj], acc[ti][tj], 0, 0, 0);
  }

  // epilogue: C/D layout col = lane&15, row = quad*4 + r
  #pragma unroll
  for (int ti = 0; ti < 4; ti++) {
    #pragma unroll
    for (int tj = 0; tj < 4; tj++) {
      int n = n0 + wn + tj * 16 + fr;
      float bias = biasf[n];
      #pragma unroll
      for (int r = 0; r < 4; r++) {
        int m = m0 + wm + ti * 16 + quad * 4 + r;
        int b = m >> 8, s = m & 255;
        float val = acc[ti][tj][r] + bias;
        if (n < 768) {
          int h = n / 24, d = n - h * 24;
          qout[(((size_t)b * H_ + h) * S_ + s) * D_ + d] = (bf16)val;
        } else if (n < 1536) {
          int n2 = n - 768;
          int h = n2 / 24, d = n2 - h * 24;
          kout[(((size_t)b * H_ + h) * S_ + s) * D_ + d] = (bf16)val;
        } else if (n < 1632) {
          int nn = n - 1536, x = nn >> 5, h = nn & 31;
          vwout[(((size_t)x * B_ + b) * H_ + h) * S_ + s] = val;
        }
      }
    }
  }
}

// ---------------------------------------------------------------------------
// Attention v2: grid = (b,h,stile) 4096 blocks, 64 s-rows each.
// Lane owns t = 4*lane..4*lane+3: K rows in REGISTERS (96 VGPR, loaded once),
// vw in registers, bias/dp as coalesced float4 loads, q via LDS broadcasts.
// Wave handles one s per iter: shuffle softmax, atomicAdd 3 floats.
// ---------------------------------------------------------------------------
__global__ __launch_bounds__(256, 3) void attn_kernel(
    const bf16* __restrict__ qg, const bf16* __restrict__ kg,
    const float* __restrict__ vwg, const float* __restrict__ biasg,
    const float* __restrict__ dpg, float* __restrict__ out)
{
  __shared__ float ql[64 * 26];
  int blk = blockIdx.x;
  int bh = blk >> 2, st = (blk & 3) * 64;
  int b = bh >> 5, h = bh & 31;
  int tid = threadIdx.x, wave = tid >> 6, lane = tid & 63;
  int t0 = lane * 4;

  // K rows t0..t0+3 -> registers (fp32 pairs)
  f32x2 kr[4][12];
  #pragma unroll
  for (int j = 0; j < 4; j++) {
    const bf16* krow = kg + ((size_t)bh * S_ + t0 + j) * D_;
    #pragma unroll
    for (int i = 0; i < 12; i++) {
      f32x2 kk;
      kk.x = (float)krow[2 * i];
      kk.y = (float)krow[2 * i + 1];
      kr[j][i] = kk;
    }
  }
  // vw for this lane's 4 t's, 3 dims
  float vwr[3][4];
  #pragma unroll
  for (int x = 0; x < 3; x++) {
    float4 v4 = *reinterpret_cast<const float4*>(
        vwg + (((size_t)x * B_ + b) * H_ + h) * S_ + t0);
    vwr[x][0] = v4.x; vwr[x][1] = v4.y; vwr[x][2] = v4.z; vwr[x][3] = v4.w;
  }
  // stage q tile (64 rows x 24) as fp32 in LDS
  {
    int r = tid >> 2, c0 = (tid & 3) * 6;
    const bf16* qrow = qg + ((size_t)bh * S_ + st + r) * D_ + c0;
    #pragma unroll
    for (int i = 0; i < 6; i++) ql[r * 26 + c0 + i] = (float)qrow[i];
  }
  __syncthreads();

  const float* biasbh = biasg + (size_t)bh * S_ * S_;

  for (int si = 0; si < 16; si++) {
    int sr = si * 4 + wave;       // row within tile
    int s = st + sr;              // global s
    // independent loads up front
    float4 bias4 = *reinterpret_cast<const float4*>(biasbh + s * S_ + t0);
    const float* dpr = dpg + ((size_t)(b * S_ + s) * S_) * 3 + (size_t)t0 * 3;
    float4 d0 = *reinterpret_cast<const float4*>(dpr);
    float4 d1 = *reinterpret_cast<const float4*>(dpr + 4);
    float4 d2 = *reinterpret_cast<const float4*>(dpr + 8);

    // scores: sc[j] = q(s) . k(t0+j)  (float2 lanes -> pk fma)
    f32x2 sc2[4];
    #pragma unroll
    for (int j = 0; j < 4; j++) { sc2[j].x = 0.f; sc2[j].y = 0.f; }
    #pragma unroll
    for (int i = 0; i < 12; i++) {
      f32x2 qd = *reinterpret_cast<const f32x2*>(&ql[sr * 26 + 2 * i]);
      #pragma unroll
      for (int j = 0; j < 4; j++) sc2[j] += qd * kr[j][i];
    }
    float sc[4];
    sc[0] = sc2[0].x + sc2[0].y + bias4.x;
    sc[1] = sc2[1].x + sc2[1].y + bias4.y;
    sc[2] = sc2[2].x + sc2[2].y + bias4.z;
    sc[3] = sc2[3].x + sc2[3].y + bias4.w;

    float mx = fmaxf(fmaxf(sc[0], sc[1]), fmaxf(sc[2], sc[3]));
    #pragma unroll
    for (int o = 32; o; o >>= 1) mx = fmaxf(mx, __shfl_xor(mx, o));
    float p[4], l = 0.f;
    #pragma unroll
    for (int j = 0; j < 4; j++) { p[j] = __expf(sc[j] - mx); l += p[j]; }
    #pragma unroll
    for (int o = 32; o; o >>= 1) l += __shfl_xor(l, o);
    float inv = 1.0f / l;

    // unpack dp (t-major xyz) from the 3 float4s
    float dx[4] = {d0.x, d0.w, d1.z, d2.y};
    float dy[4] = {d0.y, d1.x, d1.w, d2.z};
    float dz[4] = {d0.z, d1.y, d2.x, d2.w};

    float ax = 0.f, ay = 0.f, az = 0.f;
    #pragma unroll
    for (int j = 0; j < 4; j++) {
      float w = p[j] * inv;
      ax += w * dx[j] * vwr[0][j];
      ay += w * dy[j] * vwr[1][j];
      az += w * dz[j] * vwr[2][j];
    }
    #pragma unroll
    for (int o = 32; o; o >>= 1) {
      ax += __shfl_xor(ax, o);
      ay += __shfl_xor(ay, o);
      az += __shfl_xor(az, o);
    }
    if (lane == 0) {
      float* op = out + (size_t)(b * S_ + s) * 3;
      atomicAdd(op + 0, ax);
      atomicAdd(op + 1, ay);
      atomicAdd(op + 2, az);
    }
  }
}

// ---------------------------------------------------------------------------
extern "C" void kernel_launch(void* const* d_in, const int* in_sizes, int n_in,
                              void* d_out, int out_size, void* d_ws, size_t ws_size,
                              hipStream_t stream)
{
  const float* feats     = (const float*)d_in[0];
  const float* attn_bias = (const float*)d_in[1];
  const float* delta_pos = (const float*)d_in[2];
  const float* Wq        = (const float*)d_in[3];
  const float* bq        = (const float*)d_in[4];
  const float* Wk        = (const float*)d_in[5];
  const float* bk        = (const float*)d_in[6];
  const float* Wv        = (const float*)d_in[7];
  const float* bv        = (const float*)d_in[8];
  const float* Wfx       = (const float*)d_in[9];
  const float* Wfy       = (const float*)d_in[10];
  const float* Wfz       = (const float*)d_in[11];

  char* ws = (char*)d_ws;
  size_t off = 0;
  auto alloc = [&](size_t bytes) -> void* {
    void* p = ws + off;
    off = (off + bytes + 255) & ~(size_t)255;
    return p;
  };
  bf16*  ws_fb   = (bf16*) alloc((size_t)B_ * S_ * E_ * 2);        // feats bf16
  bf16*  ws_q    = (bf16*) alloc((size_t)B_ * H_ * S_ * D_ * 2);
  bf16*  ws_k    = (bf16*) alloc((size_t)B_ * H_ * S_ * D_ * 2);
  float* ws_vw   = (float*)alloc((size_t)3 * B_ * H_ * S_ * 4);
  bf16*  ws_Wt   = (bf16*) alloc((size_t)NTOT * E_ * 2);
  float* ws_bias = (float*)alloc((size_t)NTOT * 4);

  // fp32 output accumulated by attn_kernel; poisoned before timed launches
  hipMemsetAsync(d_out, 0, (size_t)B_ * S_ * 3 * 4, stream);

  int n4 = B_ * S_ * E_ / 4;
  cast_feats<<<(n4 + 255) / 256, 256, 0, stream>>>(feats, ws_fb, n4);

  int prep_n = NTOT * E_ + NTOT;
  prep_pack<<<(prep_n + 255) / 256, 256, 0, stream>>>(
      Wq, Wk, Wv, bq, bk, bv, Wfx, Wfy, Wfz, ws_Wt, ws_bias);

  gemm_qkv<<<dim3(NTOT / 128, B_ * S_ / 128), 256, 0, stream>>>(
      ws_fb, ws_Wt, ws_bias, ws_q, ws_k, ws_vw);

  attn_kernel<<<B_ * H_ * 4, 256, 0, stream>>>(ws_q, ws_k, ws_vw, attn_bias,
                                               delta_pos, (float*)d_out);
}